// Round 20
// baseline (1289.876 us; speedup 1.0000x reference)
//
#include <hip/hip_runtime.h>

// Problem constants
#define SEQ   2048
#define NBAT  2
#define MTOT  4096        // NBAT*SEQ
#define DIMC  1024
#define DFFC  4096
#define NEXP  8
#define NHEAD 16

typedef unsigned short u16;
typedef unsigned int   u32;
typedef unsigned long long u64;
typedef __attribute__((ext_vector_type(8)))  _Float16       f16x8;
typedef __attribute__((ext_vector_type(8)))  unsigned short us8;
typedef __attribute__((ext_vector_type(4)))  float          f32x4;
typedef __attribute__((ext_vector_type(16))) float          f32x16;

__device__ __forceinline__ u16 cvt16(float a) {
  return __builtin_bit_cast(u16, (_Float16)a);
}
__device__ __forceinline__ f16x8 ld_f16(const u16* p) {
  return __builtin_bit_cast(f16x8, *(const us8*)p);
}
__device__ __forceinline__ f32x4 mfma16(f16x8 a, f16x8 b, f32x4 c) {
  return __builtin_amdgcn_mfma_f32_16x16x32_f16(a, b, c, 0, 0, 0);
}
__device__ __forceinline__ f32x16 mfma32f(f16x8 a, f16x8 b, f32x16 c) {
  return __builtin_amdgcn_mfma_f32_32x32x16_f16(a, b, c, 0, 0, 0);
}
// async global->LDS, 16B per lane: dst = wave-uniform base + lane*16
__device__ __forceinline__ void gload16(const u16* g, u16* l) {
  __builtin_amdgcn_global_load_lds(
      (const __attribute__((address_space(1))) void*)g,
      (__attribute__((address_space(3))) void*)l, 16, 0, 0);
}

// ===========================================================================
// fp16 MFMA GEMM, ROUND-20: T3-minimum 2-phase double buffer, ONE barrier
// per K-tile.  Loop: STAGE(t+1 -> buf^1) ; COMPUTE(buf) ; __syncthreads.
// The 8 gloads for tile t+1 fly during tile t's 32 MFMA + ds_reads; the
// single barrier both drains vmcnt (stage complete) and fences reads-of-buf.
// r8 tried this structure with the broken staging map (masked); never tested
// with the r10 coalesced map + BK=64.  128x128 tile, 4 waves 64x64, LDS
// 64 KB (2 x 32 KB), ~2 blocks/CU (r14: occupancy >2 blocks buys nothing).
// Staging map & swizzle identical to r17 (proven): per instr 8 rows x 128 B;
// chunk-XOR c' = c ^ (row&7) on BOTH gload source and frag read.
// zmode: 0 none; 1 MoE1 (z: B,C16,bias); 3 proj split-K2; 4 MoE2 whole-K.
// ===========================================================================
template<bool WF32, bool WF16>
__global__ __launch_bounds__(256)
void pgemm16_kernel(const u16* __restrict__ A16, int lda,
                    const u16* __restrict__ B16, int ldb, int K,
                    float* __restrict__ Cf, u16* __restrict__ Ch, int ldc,
                    const float* __restrict__ bias,
                    const float* __restrict__ residual,
                    const float* __restrict__ row_scale, int rs_stride,
                    int do_relu, int do_accum,
                    int zmode, long sAZ, long sBZ, long sCZ, int sbias)
{
  const int z = blockIdx.z;
  if (zmode == 1) {
    B16 += (size_t)z * sBZ;
    Ch  += (size_t)z * sCZ;
    bias += (size_t)z * sbias;
  } else if (zmode == 3) {
    A16 += (size_t)z * sAZ;  B16 += (size_t)z * sAZ;   // k-offset
    Cf  += (size_t)z * sCZ;
    if (!z) { bias = nullptr; residual = nullptr; }
  } else if (zmode == 4) {
    A16 += (size_t)z * sAZ;
    B16 += (size_t)z * sBZ;
    Cf  += (size_t)z * sCZ;
    bias += (size_t)z * sbias;
    row_scale += z;
  }

  // XCD-aware swizzle within the 2D slice (x*y % 8 == 0 at all call sites)
  const int gx = gridDim.x;
  int bid = blockIdx.y * gx + blockIdx.x;
  const int cpx = (gx * gridDim.y) >> 3;
  bid = (bid & 7) * cpx + (bid >> 3);
  const int m0 = (bid / gx) * 128, n0 = (bid % gx) * 128;

  __shared__ __align__(16) u16 As[2][128][64];   // 2 x 16 KB
  __shared__ __align__(16) u16 Bs[2][128][64];   // 2 x 16 KB
  const int t = threadIdx.x;
  const int wid = t >> 6, lane = t & 63;
  const int wr = wid >> 1, wc = wid & 1;
  const int l15 = lane & 15, l4 = lane >> 4;

  f32x4 acc[4][4];
#pragma unroll
  for (int i = 0; i < 4; ++i)
#pragma unroll
    for (int j = 0; j < 4; ++j)
#pragma unroll
      for (int r2 = 0; r2 < 4; ++r2) acc[i][j][r2] = 0.f;

  // Staging: wave w, instr j covers rows (w*4+j)*8 .. +8; lane l -> row
  // +(l>>3), LDS chunk l&7; global chunk (l&7)^(l>>3)  (row&7 == l>>3).
  const int srow = wid * 32 + (lane >> 3);          // + j*8 per instr
  const int cs   = (((lane & 7) ^ (lane >> 3))) * 8;
  const int slotA = wid * 2048;                     // + j*512 per instr (u16)
  const u16* gA = A16 + (size_t)(m0 + srow) * lda + cs;
  const u16* gB = B16 + (size_t)(n0 + srow) * ldb + cs;

  const int fswz = l15 & 7;

#define STAGE(k0_, b_)                                                       \
  {                                                                          \
    _Pragma("unroll")                                                        \
    for (int j = 0; j < 4; ++j) {                                            \
      gload16(gA + (size_t)(j * 8) * lda + (k0_),                            \
              (u16*)As[b_] + slotA + j * 512);                               \
      gload16(gB + (size_t)(j * 8) * ldb + (k0_),                            \
              (u16*)Bs[b_] + slotA + j * 512);                               \
    }                                                                        \
  }

  const int NT = K >> 6;
  STAGE(0, 0);
  __syncthreads();                    // tile 0 landed
  int cur = 0;
  for (int tt = 0; tt < NT; ++tt) {
    if (tt + 1 < NT) STAGE((tt + 1) << 6, cur ^ 1);  // flies during compute

#pragma unroll
    for (int h = 0; h < 2; ++h) {
      const int kc = ((h * 4 + l4) ^ fswz) * 8;
      f16x8 af[4], bf[4];
#pragma unroll
      for (int mf = 0; mf < 4; ++mf)
        af[mf] = ld_f16(&As[cur][wr * 64 + mf * 16 + l15][kc]);
#pragma unroll
      for (int nf = 0; nf < 4; ++nf)
        bf[nf] = ld_f16(&Bs[cur][wc * 64 + nf * 16 + l15][kc]);
#pragma unroll
      for (int mf = 0; mf < 4; ++mf)
#pragma unroll
        for (int nf = 0; nf < 4; ++nf)
          acc[mf][nf] = mfma16(af[mf], bf[nf], acc[mf][nf]);
    }
    __syncthreads();                  // drains stage(t+1); fences buf reads
    cur ^= 1;
  }
#undef STAGE

  // epilogue: 16x16 C/D layout col=lane&15, row=(lane>>4)*4+r (verified)
#pragma unroll
  for (int mf = 0; mf < 4; ++mf)
#pragma unroll
    for (int nf = 0; nf < 4; ++nf) {
      const int col = n0 + wc * 64 + nf * 16 + l15;
      const float bia = bias ? bias[col] : 0.f;
#pragma unroll
      for (int r2 = 0; r2 < 4; ++r2) {
        const int row = m0 + wr * 64 + mf * 16 + l4 * 4 + r2;
        float v = acc[mf][nf][r2] + bia;
        if (do_relu)   v = fmaxf(v, 0.f);
        if (row_scale) v *= row_scale[(size_t)row * rs_stride];
        if (residual)  v += residual[(size_t)row * ldc + col];
        if (WF32) {
          float* cp = &Cf[(size_t)row * ldc + col];
          float vv = v;
          if (do_accum) vv += *cp;
          *cp = vv;
        }
        if (WF16) Ch[(size_t)row * ldc + col] = cvt16(v);
      }
    }
}

// ---------------------------------------------------------------------------
// Conversion kernels (fp32 -> fp16 single)
// ---------------------------------------------------------------------------
__global__ __launch_bounds__(256)
void cvt_rows16_kernel(const float* __restrict__ in, u16* __restrict__ o, long n4)
{
  const long g = (long)blockIdx.x * 256 + threadIdx.x;
  if (g >= n4) return;
  const float4 v = *(const float4*)&in[g * 4];
  union { u16 s[4]; u64 v64; } p;
  p.s[0] = cvt16(v.x); p.s[1] = cvt16(v.y); p.s[2] = cvt16(v.z); p.s[3] = cvt16(v.w);
  *(u64*)&o[g * 4] = p.v64;
}

__global__ __launch_bounds__(256)
void cvt_T16_kernel(const float* __restrict__ in, u16* __restrict__ o, int R, int C)
{
  __shared__ float tile[32][33];
  const size_t zo = (size_t)blockIdx.z * R * C;
  in += zo; o += zo;
  const int tx = threadIdx.x, ty = threadIdx.y;
  const int r0 = blockIdx.y * 32, c0 = blockIdx.x * 32;
#pragma unroll
  for (int i = 0; i < 4; ++i)
    tile[ty + i * 8][tx] = in[(size_t)(r0 + ty + i * 8) * C + c0 + tx];
  __syncthreads();
#pragma unroll
  for (int i = 0; i < 4; ++i)
    o[(size_t)(c0 + ty + i * 8) * R + r0 + tx] = cvt16(tile[tx][ty + i * 8]);
}

__global__ __launch_bounds__(256)
void im2c16_kernel(const float* __restrict__ x, u16* __restrict__ o)
{
  const long g = (long)blockIdx.x * 256 + threadIdx.x;
  if (g >= (long)MTOT * 3072 / 4) return;
  const long id4 = g * 4;
  const int j = (int)(id4 % 3072);
  const int m = (int)(id4 / 3072);
  const int tt = j >> 10, i = j & 1023;
  const int b = m >> 11, s = m & 2047;
  const int sr = s + tt - 1;
  float4 v = make_float4(0.f, 0.f, 0.f, 0.f);
  if (sr >= 0 && sr < SEQ) v = *(const float4*)&x[((size_t)(b * SEQ + sr) << 10) + i];
  union { u16 s[4]; u64 v64; } p;
  p.s[0] = cvt16(v.x); p.s[1] = cvt16(v.y); p.s[2] = cvt16(v.z); p.s[3] = cvt16(v.w);
  *(u64*)&o[id4] = p.v64;
}

__global__ __launch_bounds__(256)
void wpk16_kernel(const float* __restrict__ cw, u16* __restrict__ o)
{
  const long g = (long)blockIdx.x * 256 + threadIdx.x;
  if (g >= (long)1024 * 3072 / 4) return;
  const long id4 = g * 4;
  const int oc = (int)(id4 / 3072);
  const int kp = (int)(id4 % 3072);
  const int tt = kp >> 10, i = kp & 1023;
  union { u16 s[4]; u64 v64; } p;
#pragma unroll
  for (int q = 0; q < 4; ++q)
    p.s[q] = cvt16(cw[(size_t)oc * 3072 + (i + q) * 3 + tt]);
  *(u64*)&o[id4] = p.v64;
}

// ===========================================================================
// fp16 MFMA flash attention (unchanged, proven)
// ===========================================================================
__global__ __launch_bounds__(256)
void attn16_kernel(const u16* __restrict__ qkv, u16* __restrict__ ctx16)
{
  const int qt = blockIdx.x, h = blockIdx.y, b = blockIdx.z;
  const int t = threadIdx.x;
  const int w = t >> 6, lane = t & 63;
  const int l31 = lane & 31, half = lane >> 5;

  __shared__ __align__(16) u16 Ks[64 * 64];
  __shared__ __align__(16) u16 Vt[64 * 64];

  const size_t base = (size_t)b * SEQ * 3072;
  const int hoff = h * 64;
  const int q0 = qt * 128 + w * 32;

  f16x8 qh[4];
  {
    const u16* qrow = &qkv[base + (size_t)(q0 + l31) * 3072 + hoff];
#pragma unroll
    for (int ks = 0; ks < 4; ++ks) qh[ks] = ld_f16(&qrow[ks * 16 + half * 8]);
  }

  f32x16 cf[2];
#pragma unroll
  for (int nf = 0; nf < 2; ++nf)
#pragma unroll
    for (int r = 0; r < 16; ++r) cf[nf][r] = 0.f;
  float m_run = -1e30f, l_run = 0.f;

  const int kkey = t >> 2, kc = t & 3;
  const int vd = t & 63, vkg = t >> 6;

  for (int kt = 0; kt < SEQ / 64; ++kt) {
    __syncthreads();
    {
      const u16* kr = &qkv[base + (size_t)(kt * 64 + kkey) * 3072 + 1024 + hoff];
      const int swz = (kkey & 7) << 4;
#pragma unroll
      for (int i = 0; i < 2; ++i) {
        const us8 v = *(const us8*)&kr[kc * 16 + i * 8];
        *(us8*)((char*)Ks + kkey * 128 + ((kc * 32 + i * 16) ^ swz)) = v;
      }
    }
    {
      const u16* vc = &qkv[base + (size_t)(kt * 64 + vkg * 16) * 3072 + 2048 + hoff + vd];
      union { u16 s[8]; us8 v8; } V0, V1;
#pragma unroll
      for (int i = 0; i < 8; ++i) {
        V0.s[i] = vc[(size_t)i * 3072];
        V1.s[i] = vc[(size_t)(i + 8) * 3072];
      }
      const int swz = (vd & 7) << 4;
      *(us8*)((char*)Vt + vd * 128 + ((vkg * 32) ^ swz))      = V0.v8;
      *(us8*)((char*)Vt + vd * 128 + ((vkg * 32 + 16) ^ swz)) = V1.v8;
    }
    __syncthreads();

    f32x16 sf[2];
#pragma unroll
    for (int f = 0; f < 2; ++f)
#pragma unroll
      for (int r = 0; r < 16; ++r) sf[f][r] = 0.f;
#pragma unroll
    for (int ks = 0; ks < 4; ++ks) {
      const int rb = ks * 32 + half * 16;
#pragma unroll
      for (int f = 0; f < 2; ++f) {
        const int key = f * 32 + l31;
        const int off = rb ^ ((key & 7) << 4);
        const f16x8 kh = __builtin_bit_cast(f16x8, *(const us8*)((char*)Ks + key * 128 + off));
        sf[f] = mfma32f(kh, qh[ks], sf[f]);
      }
    }

    float tmax = -1e30f;
#pragma unroll
    for (int f = 0; f < 2; ++f)
#pragma unroll
      for (int r = 0; r < 16; ++r) tmax = fmaxf(tmax, sf[f][r]);
    tmax *= 0.125f;
    tmax = fmaxf(tmax, __shfl_xor(tmax, 32, 64));
    const float m_new = fmaxf(m_run, tmax);
    const float resc = __expf(m_run - m_new);
    float lt = 0.f;
#pragma unroll
    for (int f = 0; f < 2; ++f)
#pragma unroll
      for (int r = 0; r < 16; ++r) {
        const float p = __expf(__builtin_fmaf(sf[f][r], 0.125f, -m_new));
        sf[f][r] = p; lt += p;
      }
    lt += __shfl_xor(lt, 32, 64);
    l_run = l_run * resc + lt;
    m_run = m_new;
#pragma unroll
    for (int r = 0; r < 16; ++r) {
      const int qr = (r & 3) + 8 * (r >> 2) + 4 * half;
      const float rs = __shfl(resc, qr, 64);
      cf[0][r] *= rs; cf[1][r] *= rs;
    }

    u32 W0[2][4], W1[2][4];
#pragma unroll
    for (int f = 0; f < 2; ++f)
#pragma unroll
      for (int g = 0; g < 4; ++g) {
        auto p0 = __builtin_amdgcn_cvt_pkrtz(sf[f][4 * g], sf[f][4 * g + 1]);
        auto p1 = __builtin_amdgcn_cvt_pkrtz(sf[f][4 * g + 2], sf[f][4 * g + 3]);
        W0[f][g] = __builtin_bit_cast(u32, p0);
        W1[f][g] = __builtin_bit_cast(u32, p1);
      }
    f16x8 PA[4];
#pragma unroll
    for (int ks = 0; ks < 4; ++ks) {
      const int f = ks >> 1, g0 = (ks & 1) * 2;
      u32 a = W0[f][g0], b2 = W0[f][g0 + 1];
      u32 c = W1[f][g0], d2 = W1[f][g0 + 1];
      asm volatile("v_permlane32_swap_b32 %0, %1" : "+v"(a), "+v"(b2));
      asm volatile("v_permlane32_swap_b32 %0, %1" : "+v"(c), "+v"(d2));
      union { u32 w[4]; us8 v8; } pa;
      pa.w[0] = a; pa.w[1] = c; pa.w[2] = b2; pa.w[3] = d2;
      PA[ks] = __builtin_bit_cast(f16x8, pa.v8);
    }

#pragma unroll
    for (int ks = 0; ks < 4; ++ks) {
      const int rb = ks * 32 + half * 16;
#pragma unroll
      for (int nf = 0; nf < 2; ++nf) {
        const int dd = nf * 32 + l31;
        const int off = rb ^ ((dd & 7) << 4);
        const f16x8 vh = __builtin_bit_cast(f16x8, *(const us8*)((char*)Vt + dd * 128 + off));
        cf[nf] = mfma32f(PA[ks], vh, cf[nf]);
      }
    }
  }

  const float invl = 1.f / l_run;
#pragma unroll
  for (int r = 0; r < 16; ++r) {
    const int qr = (r & 3) + 8 * (r >> 2) + 4 * half;
    const float il = __shfl(invl, qr, 64);
    const size_t row = (size_t)(b * SEQ + q0 + qr) * 1024 + hoff;
#pragma unroll
    for (int nf = 0; nf < 2; ++nf)
      ctx16[row + nf * 32 + l31] = cvt16(cf[nf][r] * il);
  }
}

// ---------------------------------------------------------------------------
// LayerNorm: out = LN(in + sum_{i<nres} res[i*rstride]) * g + b; opt fp16 out.
// ---------------------------------------------------------------------------
__global__ __launch_bounds__(256)
void ln_kernel(const float* __restrict__ in, const float* __restrict__ res,
               int nres, long rstride,
               const float* __restrict__ g, const float* __restrict__ bt,
               float* __restrict__ outf, u16* __restrict__ outh)
{
  const int row = blockIdx.x, t = threadIdx.x;
  const size_t off = ((size_t)row << 10) + t * 4;
  float4 v = *(const float4*)&in[off];
  for (int i = 0; i < nres; ++i) {
    const float4 r = *(const float4*)&res[off + (size_t)i * rstride];
    v.x += r.x; v.y += r.y; v.z += r.z; v.w += r.w;
  }
  float s  = v.x + v.y + v.z + v.w;
  float ss = v.x * v.x + v.y * v.y + v.z * v.z + v.w * v.w;
#pragma unroll
  for (int o = 32; o; o >>= 1) {
    s  += __shfl_xor(s, o, 64);
    ss += __shfl_xor(ss, o, 64);
  }
  __shared__ float red[8];
  if ((t & 63) == 0) { red[(t >> 6) * 2] = s; red[(t >> 6) * 2 + 1] = ss; }
  __syncthreads();
  s  = red[0] + red[2] + red[4] + red[6];
  ss = red[1] + red[3] + red[5] + red[7];
  const float mu   = s * (1.f / 1024.f);
  const float var  = ss * (1.f / 1024.f) - mu * mu;
  const float rstd = rsqrtf(var + 1e-5f);
  const float4 gg = *(const float4*)&g[t * 4];
  const float4 bb = *(const float4*)&bt[t * 4];
  float4 o;
  o.x = (v.x - mu) * rstd * gg.x + bb.x;
  o.y = (v.y - mu) * rstd * gg.y + bb.y;
  o.z = (v.z - mu) * rstd * gg.z + bb.z;
  o.w = (v.w - mu) * rstd * gg.w + bb.w;
  if (outf) *(float4*)&outf[off] = o;
  if (outh) {
    union { u16 s[4]; u64 v64; } p;
    p.s[0] = cvt16(o.x); p.s[1] = cvt16(o.y); p.s[2] = cvt16(o.z); p.s[3] = cvt16(o.w);
    *(u64*)&outh[off] = p.v64;
  }
}

// ---------------------------------------------------------------------------
// MoE gate: probs[m, 0..7] = softmax(x[m,:] @ gate_w + gate_b). 1 wave / row.
// ---------------------------------------------------------------------------
__global__ __launch_bounds__(64)
void gate_kernel(const float* __restrict__ x, const float* __restrict__ gw,
                 const float* __restrict__ gb, float* __restrict__ probs)
{
  const int m = blockIdx.x, lane = threadIdx.x;
  float acc[8];
#pragma unroll
  for (int e = 0; e < 8; ++e) acc[e] = 0.f;
  for (int k = lane; k < 1024; k += 64) {
    const float xv = x[((size_t)m << 10) + k];
    const float4 g0 = *(const float4*)&gw[k * 8];
    const float4 g1 = *(const float4*)&gw[k * 8 + 4];
    acc[0] = __builtin_fmaf(xv, g0.x, acc[0]);
    acc[1] = __builtin_fmaf(xv, g0.y, acc[1]);
    acc[2] = __builtin_fmaf(xv, g0.z, acc[2]);
    acc[3] = __builtin_fmaf(xv, g0.w, acc[3]);
    acc[4] = __builtin_fmaf(xv, g1.x, acc[4]);
    acc[5] = __builtin_fmaf(xv, g1.y, acc[5]);
    acc[6] = __builtin_fmaf(xv, g1.z, acc[6]);
    acc[7] = __builtin_fmaf(xv, g1.w, acc[7]);
  }
#pragma unroll
  for (int o = 32; o; o >>= 1)
#pragma unroll
    for (int e = 0; e < 8; ++e) acc[e] += __shfl_xor(acc[e], o, 64);
  float lg[8], mx = -1e30f;
#pragma unroll
  for (int e = 0; e < 8; ++e) { lg[e] = acc[e] + gb[e]; mx = fmaxf(mx, lg[e]); }
  float se = 0.f;
#pragma unroll
  for (int e = 0; e < 8; ++e) { lg[e] = __expf(lg[e] - mx); se += lg[e]; }
  const float inv = 1.f / se;
  if (lane < 8) probs[(size_t)m * 8 + lane] = lg[lane] * inv;
}

// ---------------------------------------------------------------------------
extern "C" void kernel_launch(void* const* d_in, const int* in_sizes, int n_in,
                              void* d_out, int out_size, void* d_ws, size_t ws_size,
                              hipStream_t stream)
{
  const float* x      = (const float*)d_in[0];
  const float* conv_w = (const float*)d_in[1];
  const float* conv_b = (const float*)d_in[2];
  const float* wqkv   = (const float*)d_in[3];
  const float* bqkv   = (const float*)d_in[4];
  const float* wo     = (const float*)d_in[5];
  const float* bo     = (const float*)d_in[6];
  const float* ln1_g  = (const float*)d_in[7];
  const float* ln1_b  = (const float*)d_in[8];
  const float* gate_w = (const float*)d_in[9];
  const float* gate_b = (const float*)d_in[10];
  const float* w1     = (const float*)d_in[11];
  const float* b1     = (const float*)d_in[12];
  const float* w2     = (const float*)d_in[13];
  const float* b2     = (const float*)d_in[14];
  const float* ln2_g  = (const float*)d_in[15];
  const float* ln2_b  = (const float*)d_in[16];
  float* out = (float*)d_out;

  const dim3 blk256(256);
  char* W = (char*)d_ws;
#define MB(x) ((size_t)(x) << 20)
  // Layout (417 MiB total; ws >= 481 MiB proven).
  float* x1_f   = (float*)(W + MB(0));     // 16 MiB
  float* moe_f  = (float*)(W + MB(16));    // 4 x 16 MiB used
  float* probs  = (float*)(W + MB(144));   // 128 KiB
  u16* x1_h     = (u16*)(W + MB(145));     // 8 MiB
  u16* ctx16    = (u16*)(W + MB(153));     // 8 MiB
  u16* h16      = (u16*)(W + MB(161));     // 4 experts x 32 MiB = 161..289
  u16* im2c16   = (u16*)(W + MB(161));     // early tenants of h16 region
  u16* wpk16    = (u16*)(W + MB(185));
  u16* wqkv16   = (u16*)(W + MB(191));
  float* yconv_f= (float*)(W + MB(197));
  u16* yconv16  = (u16*)(W + MB(213));
  u16* qkv16    = (u16*)(W + MB(221));     // 24 MiB
  u16* wo16     = (u16*)(W + MB(245));
  float* res1a  = (float*)(W + MB(247));
  float* res1b  = (float*)(W + MB(263));   // ends 279 < 289 OK
  u16* w1s16    = (u16*)(W + MB(289));     // 64 MiB
  u16* w2s16    = (u16*)(W + MB(353));     // 64 MiB -> ends 417

  // ---- conversions ----
  im2c16_kernel<<<dim3(12288), blk256, 0, stream>>>(x, im2c16);
  wpk16_kernel<<<dim3(3072), blk256, 0, stream>>>(conv_w, wpk16);
  cvt_rows16_kernel<<<dim3(3072), blk256, 0, stream>>>(wqkv, wqkv16, 786432);
  cvt_rows16_kernel<<<dim3(1024), blk256, 0, stream>>>(wo, wo16, 262144);
  cvt_T16_kernel<<<dim3(128, 32, 8), dim3(32, 8), 0, stream>>>(w1, w1s16, 1024, 4096);
  cvt_T16_kernel<<<dim3(32, 128, 8), dim3(32, 8), 0, stream>>>(w2, w2s16, 4096, 1024);

  // ---- conv GEMM ----
  pgemm16_kernel<true, true><<<dim3(8, 32, 1), blk256, 0, stream>>>(
      im2c16, 3072, wpk16, 3072, 3072,
      yconv_f, yconv16, 1024,
      conv_b, nullptr, nullptr, 0, 0, 0, 0, 0, 0, 0, 0);

  // ---- QKV ----
  pgemm16_kernel<false, true><<<dim3(24, 32, 1), blk256, 0, stream>>>(
      yconv16, 1024, wqkv16, 1024, 1024,
      nullptr, qkv16, 3072,
      bqkv, nullptr, nullptr, 0, 0, 0, 0, 0, 0, 0, 0);

  // ---- attention ----
  attn16_kernel<<<dim3(SEQ / 128, NHEAD, NBAT), blk256, 0, stream>>>(qkv16, ctx16);

  // ---- out projection split-K2 (K=512 per half, 512%64==0) ----
  pgemm16_kernel<true, false><<<dim3(8, 32, 2), blk256, 0, stream>>>(
      ctx16, 1024, wo16, 1024, 512,
      res1a, nullptr, 1024,
      bo, yconv_f, nullptr, 0, 0, 0,
      3, 512, 0, 4194304, 0);

  // ---- LN1 ----
  ln_kernel<<<dim3(MTOT), blk256, 0, stream>>>(
      res1a, res1b, 1, 0, ln1_g, ln1_b, x1_f, x1_h);

  // ---- gate ----
  gate_kernel<<<dim3(MTOT), dim3(64), 0, stream>>>(x1_f, gate_w, gate_b, probs);

  // ---- MoE experts 0-3 ----
  pgemm16_kernel<false, true><<<dim3(32, 32, 4), blk256, 0, stream>>>(
      x1_h, 1024, w1s16, 1024, 1024,
      nullptr, h16, 4096,
      b1, nullptr, nullptr, 0, 1 /*relu*/, 0,
      1, 0, 4194304, 16777216, 4096);
  pgemm16_kernel<true, false><<<dim3(8, 32, 4), blk256, 0, stream>>>(
      h16, 4096, w2s16, 4096, 4096 /*whole K*/,
      moe_f, nullptr, 1024,
      b2, nullptr, probs, 8, 0, 0 /*no accum*/,
      4, 16777216, 4194304, 4194304, 1024);

  // ---- MoE experts 4-7 (h16 reused; accumulate into same 4 moe bufs) ----
  pgemm16_kernel<false, true><<<dim3(32, 32, 4), blk256, 0, stream>>>(
      x1_h, 1024, w1s16 + (size_t)4 * 4194304, 1024, 1024,
      nullptr, h16, 4096,
      b1 + 4 * 4096, nullptr, nullptr, 0, 1, 0,
      1, 0, 4194304, 16777216, 4096);
  pgemm16_kernel<true, false><<<dim3(8, 32, 4), blk256, 0, stream>>>(
      h16, 4096, w2s16 + (size_t)4 * 4194304, 4096, 4096,
      moe_f, nullptr, 1024,
      b2 + 4 * 1024, nullptr, probs + 4, 8, 0, 1 /*accum*/,
      4, 16777216, 4194304, 4194304, 1024);

  // ---- LN2(x1 + sum of 4 moe bufs) -> out ----
  ln_kernel<<<dim3(MTOT), blk256, 0, stream>>>(
      x1_f, moe_f, 4, 4194304, ln2_g, ln2_b, out, nullptr);
#undef MB
}

// Round 21
// 1177.048 us; speedup vs baseline: 1.0959x; 1.0959x over previous
//
#include <hip/hip_runtime.h>

// Problem constants
#define SEQ   2048
#define NBAT  2
#define MTOT  4096        // NBAT*SEQ
#define DIMC  1024
#define DFFC  4096
#define NEXP  8
#define NHEAD 16

typedef unsigned short u16;
typedef unsigned int   u32;
typedef unsigned long long u64;
typedef __attribute__((ext_vector_type(8)))  _Float16       f16x8;
typedef __attribute__((ext_vector_type(8)))  unsigned short us8;
typedef __attribute__((ext_vector_type(4)))  float          f32x4;
typedef __attribute__((ext_vector_type(16))) float          f32x16;

__device__ __forceinline__ u16 cvt16(float a) {
  return __builtin_bit_cast(u16, (_Float16)a);
}
__device__ __forceinline__ f16x8 ld_f16(const u16* p) {
  return __builtin_bit_cast(f16x8, *(const us8*)p);
}
__device__ __forceinline__ f32x4 mfma16(f16x8 a, f16x8 b, f32x4 c) {
  return __builtin_amdgcn_mfma_f32_16x16x32_f16(a, b, c, 0, 0, 0);
}
__device__ __forceinline__ f32x16 mfma32f(f16x8 a, f16x8 b, f32x16 c) {
  return __builtin_amdgcn_mfma_f32_32x32x16_f16(a, b, c, 0, 0, 0);
}
// async global->LDS, 16B per lane: dst = wave-uniform base + lane*16
__device__ __forceinline__ void gload16(const u16* g, u16* l) {
  __builtin_amdgcn_global_load_lds(
      (const __attribute__((address_space(1))) void*)g,
      (__attribute__((address_space(3))) void*)l, 16, 0, 0);
}

// ===========================================================================
// fp16 MFMA GEMM, m97 structure, r17 config (PROVEN BEST, 1177us total):
// BK=64, 128x128 tile, 4 waves 64x64, single 32 KB LDS (A+B), plain
// __syncthreads.  32 MFMA per barrier.  Final configuration: the schedule
// matrix {single-buf, 2-deep, 3-deep, phase-split, 2-phase-1-barrier} was
// measured; single-buffer wins (implicit inter-block overlap, m114; every
// pipelined variant pays its LDS/VGPR footprint in occupancy).
// Staging: [128][64] u16 rows (128 B); per instr 8 rows x 128 B; chunk-XOR
// swizzle c' = c ^ (row&7) on BOTH gload source ((l&7)^(l>>3)) and frag
// read ((h*4+l4)^(l15&7)) -- 2-way bank aliasing = free.
// zmode: 0 none; 1 MoE1 (z: B,C16,bias); 3 proj split-K2; 4 MoE2 whole-K.
// ===========================================================================
template<bool WF32, bool WF16>
__global__ __launch_bounds__(256)
void pgemm16_kernel(const u16* __restrict__ A16, int lda,
                    const u16* __restrict__ B16, int ldb, int K,
                    float* __restrict__ Cf, u16* __restrict__ Ch, int ldc,
                    const float* __restrict__ bias,
                    const float* __restrict__ residual,
                    const float* __restrict__ row_scale, int rs_stride,
                    int do_relu, int do_accum,
                    int zmode, long sAZ, long sBZ, long sCZ, int sbias)
{
  const int z = blockIdx.z;
  if (zmode == 1) {
    B16 += (size_t)z * sBZ;
    Ch  += (size_t)z * sCZ;
    bias += (size_t)z * sbias;
  } else if (zmode == 3) {
    A16 += (size_t)z * sAZ;  B16 += (size_t)z * sAZ;   // k-offset
    Cf  += (size_t)z * sCZ;
    if (!z) { bias = nullptr; residual = nullptr; }
  } else if (zmode == 4) {
    A16 += (size_t)z * sAZ;
    B16 += (size_t)z * sBZ;
    Cf  += (size_t)z * sCZ;
    bias += (size_t)z * sbias;
    row_scale += z;
  }

  // XCD-aware swizzle within the 2D slice (x*y % 8 == 0 at all call sites)
  const int gx = gridDim.x;
  int bid = blockIdx.y * gx + blockIdx.x;
  const int cpx = (gx * gridDim.y) >> 3;
  bid = (bid & 7) * cpx + (bid >> 3);
  const int m0 = (bid / gx) * 128, n0 = (bid % gx) * 128;

  __shared__ __align__(16) u16 As[128][64];   // 16 KB (single buffer)
  __shared__ __align__(16) u16 Bs[128][64];   // 16 KB
  const int t = threadIdx.x;
  const int wid = t >> 6, lane = t & 63;
  const int wr = wid >> 1, wc = wid & 1;
  const int l15 = lane & 15, l4 = lane >> 4;

  f32x4 acc[4][4];
#pragma unroll
  for (int i = 0; i < 4; ++i)
#pragma unroll
    for (int j = 0; j < 4; ++j)
#pragma unroll
      for (int r2 = 0; r2 < 4; ++r2) acc[i][j][r2] = 0.f;

  // Staging: wave w, instr j covers rows (w*4+j)*8 .. +8; lane l -> row
  // +(l>>3), LDS chunk l&7; global chunk (l&7)^(l>>3)  (row&7 == l>>3).
  const int srow = wid * 32 + (lane >> 3);          // + j*8 per instr
  const int cs   = (((lane & 7) ^ (lane >> 3))) * 8;
  const int slotA = wid * 2048;                     // + j*512 per instr (u16)
  const u16* gA = A16 + (size_t)(m0 + srow) * lda + cs;
  const u16* gB = B16 + (size_t)(n0 + srow) * ldb + cs;

  const int fswz = l15 & 7;

  const int NT = K >> 6;
  for (int tt = 0; tt < NT; ++tt) {
    const int k0 = tt << 6;
    if (tt) __syncthreads();
#pragma unroll
    for (int j = 0; j < 4; ++j) {
      gload16(gA + (size_t)(j * 8) * lda + k0, (u16*)As + slotA + j * 512);
      gload16(gB + (size_t)(j * 8) * ldb + k0, (u16*)Bs + slotA + j * 512);
    }
    __syncthreads();

#pragma unroll
    for (int h = 0; h < 2; ++h) {
      const int kc = ((h * 4 + l4) ^ fswz) * 8;
      f16x8 af[4], bf[4];
#pragma unroll
      for (int mf = 0; mf < 4; ++mf)
        af[mf] = ld_f16(&As[wr * 64 + mf * 16 + l15][kc]);
#pragma unroll
      for (int nf = 0; nf < 4; ++nf)
        bf[nf] = ld_f16(&Bs[wc * 64 + nf * 16 + l15][kc]);
#pragma unroll
      for (int mf = 0; mf < 4; ++mf)
#pragma unroll
        for (int nf = 0; nf < 4; ++nf)
          acc[mf][nf] = mfma16(af[mf], bf[nf], acc[mf][nf]);
    }
  }

  // epilogue: 16x16 C/D layout col=lane&15, row=(lane>>4)*4+r (verified)
#pragma unroll
  for (int mf = 0; mf < 4; ++mf)
#pragma unroll
    for (int nf = 0; nf < 4; ++nf) {
      const int col = n0 + wc * 64 + nf * 16 + l15;
      const float bia = bias ? bias[col] : 0.f;
#pragma unroll
      for (int r2 = 0; r2 < 4; ++r2) {
        const int row = m0 + wr * 64 + mf * 16 + l4 * 4 + r2;
        float v = acc[mf][nf][r2] + bia;
        if (do_relu)   v = fmaxf(v, 0.f);
        if (row_scale) v *= row_scale[(size_t)row * rs_stride];
        if (residual)  v += residual[(size_t)row * ldc + col];
        if (WF32) {
          float* cp = &Cf[(size_t)row * ldc + col];
          float vv = v;
          if (do_accum) vv += *cp;
          *cp = vv;
        }
        if (WF16) Ch[(size_t)row * ldc + col] = cvt16(v);
      }
    }
}

// ---------------------------------------------------------------------------
// Conversion kernels (fp32 -> fp16 single)
// ---------------------------------------------------------------------------
__global__ __launch_bounds__(256)
void cvt_rows16_kernel(const float* __restrict__ in, u16* __restrict__ o, long n4)
{
  const long g = (long)blockIdx.x * 256 + threadIdx.x;
  if (g >= n4) return;
  const float4 v = *(const float4*)&in[g * 4];
  union { u16 s[4]; u64 v64; } p;
  p.s[0] = cvt16(v.x); p.s[1] = cvt16(v.y); p.s[2] = cvt16(v.z); p.s[3] = cvt16(v.w);
  *(u64*)&o[g * 4] = p.v64;
}

__global__ __launch_bounds__(256)
void cvt_T16_kernel(const float* __restrict__ in, u16* __restrict__ o, int R, int C)
{
  __shared__ float tile[32][33];
  const size_t zo = (size_t)blockIdx.z * R * C;
  in += zo; o += zo;
  const int tx = threadIdx.x, ty = threadIdx.y;
  const int r0 = blockIdx.y * 32, c0 = blockIdx.x * 32;
#pragma unroll
  for (int i = 0; i < 4; ++i)
    tile[ty + i * 8][tx] = in[(size_t)(r0 + ty + i * 8) * C + c0 + tx];
  __syncthreads();
#pragma unroll
  for (int i = 0; i < 4; ++i)
    o[(size_t)(c0 + ty + i * 8) * R + r0 + tx] = cvt16(tile[tx][ty + i * 8]);
}

__global__ __launch_bounds__(256)
void im2c16_kernel(const float* __restrict__ x, u16* __restrict__ o)
{
  const long g = (long)blockIdx.x * 256 + threadIdx.x;
  if (g >= (long)MTOT * 3072 / 4) return;
  const long id4 = g * 4;
  const int j = (int)(id4 % 3072);
  const int m = (int)(id4 / 3072);
  const int tt = j >> 10, i = j & 1023;
  const int b = m >> 11, s = m & 2047;
  const int sr = s + tt - 1;
  float4 v = make_float4(0.f, 0.f, 0.f, 0.f);
  if (sr >= 0 && sr < SEQ) v = *(const float4*)&x[((size_t)(b * SEQ + sr) << 10) + i];
  union { u16 s[4]; u64 v64; } p;
  p.s[0] = cvt16(v.x); p.s[1] = cvt16(v.y); p.s[2] = cvt16(v.z); p.s[3] = cvt16(v.w);
  *(u64*)&o[id4] = p.v64;
}

__global__ __launch_bounds__(256)
void wpk16_kernel(const float* __restrict__ cw, u16* __restrict__ o)
{
  const long g = (long)blockIdx.x * 256 + threadIdx.x;
  if (g >= (long)1024 * 3072 / 4) return;
  const long id4 = g * 4;
  const int oc = (int)(id4 / 3072);
  const int kp = (int)(id4 % 3072);
  const int tt = kp >> 10, i = kp & 1023;
  union { u16 s[4]; u64 v64; } p;
#pragma unroll
  for (int q = 0; q < 4; ++q)
    p.s[q] = cvt16(cw[(size_t)oc * 3072 + (i + q) * 3 + tt]);
  *(u64*)&o[id4] = p.v64;
}

// ===========================================================================
// fp16 MFMA flash attention (unchanged, proven)
// ===========================================================================
__global__ __launch_bounds__(256)
void attn16_kernel(const u16* __restrict__ qkv, u16* __restrict__ ctx16)
{
  const int qt = blockIdx.x, h = blockIdx.y, b = blockIdx.z;
  const int t = threadIdx.x;
  const int w = t >> 6, lane = t & 63;
  const int l31 = lane & 31, half = lane >> 5;

  __shared__ __align__(16) u16 Ks[64 * 64];
  __shared__ __align__(16) u16 Vt[64 * 64];

  const size_t base = (size_t)b * SEQ * 3072;
  const int hoff = h * 64;
  const int q0 = qt * 128 + w * 32;

  f16x8 qh[4];
  {
    const u16* qrow = &qkv[base + (size_t)(q0 + l31) * 3072 + hoff];
#pragma unroll
    for (int ks = 0; ks < 4; ++ks) qh[ks] = ld_f16(&qrow[ks * 16 + half * 8]);
  }

  f32x16 cf[2];
#pragma unroll
  for (int nf = 0; nf < 2; ++nf)
#pragma unroll
    for (int r = 0; r < 16; ++r) cf[nf][r] = 0.f;
  float m_run = -1e30f, l_run = 0.f;

  const int kkey = t >> 2, kc = t & 3;
  const int vd = t & 63, vkg = t >> 6;

  for (int kt = 0; kt < SEQ / 64; ++kt) {
    __syncthreads();
    {
      const u16* kr = &qkv[base + (size_t)(kt * 64 + kkey) * 3072 + 1024 + hoff];
      const int swz = (kkey & 7) << 4;
#pragma unroll
      for (int i = 0; i < 2; ++i) {
        const us8 v = *(const us8*)&kr[kc * 16 + i * 8];
        *(us8*)((char*)Ks + kkey * 128 + ((kc * 32 + i * 16) ^ swz)) = v;
      }
    }
    {
      const u16* vc = &qkv[base + (size_t)(kt * 64 + vkg * 16) * 3072 + 2048 + hoff + vd];
      union { u16 s[8]; us8 v8; } V0, V1;
#pragma unroll
      for (int i = 0; i < 8; ++i) {
        V0.s[i] = vc[(size_t)i * 3072];
        V1.s[i] = vc[(size_t)(i + 8) * 3072];
      }
      const int swz = (vd & 7) << 4;
      *(us8*)((char*)Vt + vd * 128 + ((vkg * 32) ^ swz))      = V0.v8;
      *(us8*)((char*)Vt + vd * 128 + ((vkg * 32 + 16) ^ swz)) = V1.v8;
    }
    __syncthreads();

    f32x16 sf[2];
#pragma unroll
    for (int f = 0; f < 2; ++f)
#pragma unroll
      for (int r = 0; r < 16; ++r) sf[f][r] = 0.f;
#pragma unroll
    for (int ks = 0; ks < 4; ++ks) {
      const int rb = ks * 32 + half * 16;
#pragma unroll
      for (int f = 0; f < 2; ++f) {
        const int key = f * 32 + l31;
        const int off = rb ^ ((key & 7) << 4);
        const f16x8 kh = __builtin_bit_cast(f16x8, *(const us8*)((char*)Ks + key * 128 + off));
        sf[f] = mfma32f(kh, qh[ks], sf[f]);
      }
    }

    float tmax = -1e30f;
#pragma unroll
    for (int f = 0; f < 2; ++f)
#pragma unroll
      for (int r = 0; r < 16; ++r) tmax = fmaxf(tmax, sf[f][r]);
    tmax *= 0.125f;
    tmax = fmaxf(tmax, __shfl_xor(tmax, 32, 64));
    const float m_new = fmaxf(m_run, tmax);
    const float resc = __expf(m_run - m_new);
    float lt = 0.f;
#pragma unroll
    for (int f = 0; f < 2; ++f)
#pragma unroll
      for (int r = 0; r < 16; ++r) {
        const float p = __expf(__builtin_fmaf(sf[f][r], 0.125f, -m_new));
        sf[f][r] = p; lt += p;
      }
    lt += __shfl_xor(lt, 32, 64);
    l_run = l_run * resc + lt;
    m_run = m_new;
#pragma unroll
    for (int r = 0; r < 16; ++r) {
      const int qr = (r & 3) + 8 * (r >> 2) + 4 * half;
      const float rs = __shfl(resc, qr, 64);
      cf[0][r] *= rs; cf[1][r] *= rs;
    }

    u32 W0[2][4], W1[2][4];
#pragma unroll
    for (int f = 0; f < 2; ++f)
#pragma unroll
      for (int g = 0; g < 4; ++g) {
        auto p0 = __builtin_amdgcn_cvt_pkrtz(sf[f][4 * g], sf[f][4 * g + 1]);
        auto p1 = __builtin_amdgcn_cvt_pkrtz(sf[f][4 * g + 2], sf[f][4 * g + 3]);
        W0[f][g] = __builtin_bit_cast(u32, p0);
        W1[f][g] = __builtin_bit_cast(u32, p1);
      }
    f16x8 PA[4];
#pragma unroll
    for (int ks = 0; ks < 4; ++ks) {
      const int f = ks >> 1, g0 = (ks & 1) * 2;
      u32 a = W0[f][g0], b2 = W0[f][g0 + 1];
      u32 c = W1[f][g0], d2 = W1[f][g0 + 1];
      asm volatile("v_permlane32_swap_b32 %0, %1" : "+v"(a), "+v"(b2));
      asm volatile("v_permlane32_swap_b32 %0, %1" : "+v"(c), "+v"(d2));
      union { u32 w[4]; us8 v8; } pa;
      pa.w[0] = a; pa.w[1] = c; pa.w[2] = b2; pa.w[3] = d2;
      PA[ks] = __builtin_bit_cast(f16x8, pa.v8);
    }

#pragma unroll
    for (int ks = 0; ks < 4; ++ks) {
      const int rb = ks * 32 + half * 16;
#pragma unroll
      for (int nf = 0; nf < 2; ++nf) {
        const int dd = nf * 32 + l31;
        const int off = rb ^ ((dd & 7) << 4);
        const f16x8 vh = __builtin_bit_cast(f16x8, *(const us8*)((char*)Vt + dd * 128 + off));
        cf[nf] = mfma32f(PA[ks], vh, cf[nf]);
      }
    }
  }

  const float invl = 1.f / l_run;
#pragma unroll
  for (int r = 0; r < 16; ++r) {
    const int qr = (r & 3) + 8 * (r >> 2) + 4 * half;
    const float il = __shfl(invl, qr, 64);
    const size_t row = (size_t)(b * SEQ + q0 + qr) * 1024 + hoff;
#pragma unroll
    for (int nf = 0; nf < 2; ++nf)
      ctx16[row + nf * 32 + l31] = cvt16(cf[nf][r] * il);
  }
}

// ---------------------------------------------------------------------------
// LayerNorm: out = LN(in + sum_{i<nres} res[i*rstride]) * g + b; opt fp16 out.
// ---------------------------------------------------------------------------
__global__ __launch_bounds__(256)
void ln_kernel(const float* __restrict__ in, const float* __restrict__ res,
               int nres, long rstride,
               const float* __restrict__ g, const float* __restrict__ bt,
               float* __restrict__ outf, u16* __restrict__ outh)
{
  const int row = blockIdx.x, t = threadIdx.x;
  const size_t off = ((size_t)row << 10) + t * 4;
  float4 v = *(const float4*)&in[off];
  for (int i = 0; i < nres; ++i) {
    const float4 r = *(const float4*)&res[off + (size_t)i * rstride];
    v.x += r.x; v.y += r.y; v.z += r.z; v.w += r.w;
  }
  float s  = v.x + v.y + v.z + v.w;
  float ss = v.x * v.x + v.y * v.y + v.z * v.z + v.w * v.w;
#pragma unroll
  for (int o = 32; o; o >>= 1) {
    s  += __shfl_xor(s, o, 64);
    ss += __shfl_xor(ss, o, 64);
  }
  __shared__ float red[8];
  if ((t & 63) == 0) { red[(t >> 6) * 2] = s; red[(t >> 6) * 2 + 1] = ss; }
  __syncthreads();
  s  = red[0] + red[2] + red[4] + red[6];
  ss = red[1] + red[3] + red[5] + red[7];
  const float mu   = s * (1.f / 1024.f);
  const float var  = ss * (1.f / 1024.f) - mu * mu;
  const float rstd = rsqrtf(var + 1e-5f);
  const float4 gg = *(const float4*)&g[t * 4];
  const float4 bb = *(const float4*)&bt[t * 4];
  float4 o;
  o.x = (v.x - mu) * rstd * gg.x + bb.x;
  o.y = (v.y - mu) * rstd * gg.y + bb.y;
  o.z = (v.z - mu) * rstd * gg.z + bb.z;
  o.w = (v.w - mu) * rstd * gg.w + bb.w;
  if (outf) *(float4*)&outf[off] = o;
  if (outh) {
    union { u16 s[4]; u64 v64; } p;
    p.s[0] = cvt16(o.x); p.s[1] = cvt16(o.y); p.s[2] = cvt16(o.z); p.s[3] = cvt16(o.w);
    *(u64*)&outh[off] = p.v64;
  }
}

// ---------------------------------------------------------------------------
// MoE gate: probs[m, 0..7] = softmax(x[m,:] @ gate_w + gate_b). 1 wave / row.
// ---------------------------------------------------------------------------
__global__ __launch_bounds__(64)
void gate_kernel(const float* __restrict__ x, const float* __restrict__ gw,
                 const float* __restrict__ gb, float* __restrict__ probs)
{
  const int m = blockIdx.x, lane = threadIdx.x;
  float acc[8];
#pragma unroll
  for (int e = 0; e < 8; ++e) acc[e] = 0.f;
  for (int k = lane; k < 1024; k += 64) {
    const float xv = x[((size_t)m << 10) + k];
    const float4 g0 = *(const float4*)&gw[k * 8];
    const float4 g1 = *(const float4*)&gw[k * 8 + 4];
    acc[0] = __builtin_fmaf(xv, g0.x, acc[0]);
    acc[1] = __builtin_fmaf(xv, g0.y, acc[1]);
    acc[2] = __builtin_fmaf(xv, g0.z, acc[2]);
    acc[3] = __builtin_fmaf(xv, g0.w, acc[3]);
    acc[4] = __builtin_fmaf(xv, g1.x, acc[4]);
    acc[5] = __builtin_fmaf(xv, g1.y, acc[5]);
    acc[6] = __builtin_fmaf(xv, g1.z, acc[6]);
    acc[7] = __builtin_fmaf(xv, g1.w, acc[7]);
  }
#pragma unroll
  for (int o = 32; o; o >>= 1)
#pragma unroll
    for (int e = 0; e < 8; ++e) acc[e] += __shfl_xor(acc[e], o, 64);
  float lg[8], mx = -1e30f;
#pragma unroll
  for (int e = 0; e < 8; ++e) { lg[e] = acc[e] + gb[e]; mx = fmaxf(mx, lg[e]); }
  float se = 0.f;
#pragma unroll
  for (int e = 0; e < 8; ++e) { lg[e] = __expf(lg[e] - mx); se += lg[e]; }
  const float inv = 1.f / se;
  if (lane < 8) probs[(size_t)m * 8 + lane] = lg[lane] * inv;
}

// ---------------------------------------------------------------------------
extern "C" void kernel_launch(void* const* d_in, const int* in_sizes, int n_in,
                              void* d_out, int out_size, void* d_ws, size_t ws_size,
                              hipStream_t stream)
{
  const float* x      = (const float*)d_in[0];
  const float* conv_w = (const float*)d_in[1];
  const float* conv_b = (const float*)d_in[2];
  const float* wqkv   = (const float*)d_in[3];
  const float* bqkv   = (const float*)d_in[4];
  const float* wo     = (const float*)d_in[5];
  const float* bo     = (const float*)d_in[6];
  const float* ln1_g  = (const float*)d_in[7];
  const float* ln1_b  = (const float*)d_in[8];
  const float* gate_w = (const float*)d_in[9];
  const float* gate_b = (const float*)d_in[10];
  const float* w1     = (const float*)d_in[11];
  const float* b1     = (const float*)d_in[12];
  const float* w2     = (const float*)d_in[13];
  const float* b2     = (const float*)d_in[14];
  const float* ln2_g  = (const float*)d_in[15];
  const float* ln2_b  = (const float*)d_in[16];
  float* out = (float*)d_out;

  const dim3 blk256(256);
  char* W = (char*)d_ws;
#define MB(x) ((size_t)(x) << 20)
  // Layout (417 MiB total; ws >= 481 MiB proven).
  float* x1_f   = (float*)(W + MB(0));     // 16 MiB
  float* moe_f  = (float*)(W + MB(16));    // 4 x 16 MiB used
  float* probs  = (float*)(W + MB(144));   // 128 KiB
  u16* x1_h     = (u16*)(W + MB(145));     // 8 MiB
  u16* ctx16    = (u16*)(W + MB(153));     // 8 MiB
  u16* h16      = (u16*)(W + MB(161));     // 4 experts x 32 MiB = 161..289
  u16* im2c16   = (u16*)(W + MB(161));     // early tenants of h16 region
  u16* wpk16    = (u16*)(W + MB(185));
  u16* wqkv16   = (u16*)(W + MB(191));
  float* yconv_f= (float*)(W + MB(197));
  u16* yconv16  = (u16*)(W + MB(213));
  u16* qkv16    = (u16*)(W + MB(221));     // 24 MiB
  u16* wo16     = (u16*)(W + MB(245));
  float* res1a  = (float*)(W + MB(247));
  float* res1b  = (float*)(W + MB(263));   // ends 279 < 289 OK
  u16* w1s16    = (u16*)(W + MB(289));     // 64 MiB
  u16* w2s16    = (u16*)(W + MB(353));     // 64 MiB -> ends 417

  // ---- conversions ----
  im2c16_kernel<<<dim3(12288), blk256, 0, stream>>>(x, im2c16);
  wpk16_kernel<<<dim3(3072), blk256, 0, stream>>>(conv_w, wpk16);
  cvt_rows16_kernel<<<dim3(3072), blk256, 0, stream>>>(wqkv, wqkv16, 786432);
  cvt_rows16_kernel<<<dim3(1024), blk256, 0, stream>>>(wo, wo16, 262144);
  cvt_T16_kernel<<<dim3(128, 32, 8), dim3(32, 8), 0, stream>>>(w1, w1s16, 1024, 4096);
  cvt_T16_kernel<<<dim3(32, 128, 8), dim3(32, 8), 0, stream>>>(w2, w2s16, 4096, 1024);

  // ---- conv GEMM ----
  pgemm16_kernel<true, true><<<dim3(8, 32, 1), blk256, 0, stream>>>(
      im2c16, 3072, wpk16, 3072, 3072,
      yconv_f, yconv16, 1024,
      conv_b, nullptr, nullptr, 0, 0, 0, 0, 0, 0, 0, 0);

  // ---- QKV ----
  pgemm16_kernel<false, true><<<dim3(24, 32, 1), blk256, 0, stream>>>(
      yconv16, 1024, wqkv16, 1024, 1024,
      nullptr, qkv16, 3072,
      bqkv, nullptr, nullptr, 0, 0, 0, 0, 0, 0, 0, 0);

  // ---- attention ----
  attn16_kernel<<<dim3(SEQ / 128, NHEAD, NBAT), blk256, 0, stream>>>(qkv16, ctx16);

  // ---- out projection split-K2 (K=512 per half, 512%64==0) ----
  pgemm16_kernel<true, false><<<dim3(8, 32, 2), blk256, 0, stream>>>(
      ctx16, 1024, wo16, 1024, 512,
      res1a, nullptr, 1024,
      bo, yconv_f, nullptr, 0, 0, 0,
      3, 512, 0, 4194304, 0);

  // ---- LN1 ----
  ln_kernel<<<dim3(MTOT), blk256, 0, stream>>>(
      res1a, res1b, 1, 0, ln1_g, ln1_b, x1_f, x1_h);

  // ---- gate ----
  gate_kernel<<<dim3(MTOT), dim3(64), 0, stream>>>(x1_f, gate_w, gate_b, probs);

  // ---- MoE experts 0-3 ----
  pgemm16_kernel<false, true><<<dim3(32, 32, 4), blk256, 0, stream>>>(
      x1_h, 1024, w1s16, 1024, 1024,
      nullptr, h16, 4096,
      b1, nullptr, nullptr, 0, 1 /*relu*/, 0,
      1, 0, 4194304, 16777216, 4096);
  pgemm16_kernel<true, false><<<dim3(8, 32, 4), blk256, 0, stream>>>(
      h16, 4096, w2s16, 4096, 4096 /*whole K*/,
      moe_f, nullptr, 1024,
      b2, nullptr, probs, 8, 0, 0 /*no accum*/,
      4, 16777216, 4194304, 4194304, 1024);

  // ---- MoE experts 4-7 (h16 reused; accumulate into same 4 moe bufs) ----
  pgemm16_kernel<false, true><<<dim3(32, 32, 4), blk256, 0, stream>>>(
      x1_h, 1024, w1s16 + (size_t)4 * 4194304, 1024, 1024,
      nullptr, h16, 4096,
      b1 + 4 * 4096, nullptr, nullptr, 0, 1, 0,
      1, 0, 4194304, 16777216, 4096);
  pgemm16_kernel<true, false><<<dim3(8, 32, 4), blk256, 0, stream>>>(
      h16, 4096, w2s16 + (size_t)4 * 4194304, 4096, 4096,
      moe_f, nullptr, 1024,
      b2 + 4 * 1024, nullptr, probs + 4, 8, 0, 1 /*accum*/,
      4, 16777216, 4194304, 4194304, 1024);

  // ---- LN2(x1 + sum of 4 moe bufs) -> out ----
  ln_kernel<<<dim3(MTOT), blk256, 0, stream>>>(
      x1_f, moe_f, 4, 4194304, ln2_g, ln2_b, out, nullptr);
#undef MB
}